// Round 1
// baseline (3408.004 us; speedup 1.0000x reference)
//
#include <hip/hip_runtime.h>
#include <math.h>

// Problem constants
#define BB 256      // batch
#define TT 255      // T1
#define NN 128      // input channels
#define HH 256      // hidden
#define KTOT 384    // N + H (GEMM K)

// Workspace layout (floats):
//   E  : [B][N]   @ 0       (32768)   exp(score_x + attn_b)
//   h  : [B][H]   @ 32768   (65536)
//   c  : [B][H]   @ 98304   (65536)
//   s3 : [3][B]   @ 163840  (768)     triple-buffered attention scalar s[b]
// total = 164608 floats = 658,432 bytes

__device__ __forceinline__ float sigmoidf_(float v) { return 1.0f / (1.0f + __expf(-v)); }

__global__ __launch_bounds__(256) void precompute_kernel(
    const float* __restrict__ x, const float* __restrict__ attn_W,
    const float* __restrict__ attn_b, float* __restrict__ ws)
{
    float* E  = ws;
    float* h  = ws + 32768;
    float* c  = ws + 98304;
    float* s3 = ws + 163840;

    const int tid  = threadIdx.x;
    const int gtid = blockIdx.x * 256 + tid;   // 0..32767 over 128 blocks

    // zero recurrent state + all 3 s buffers (ws is poisoned 0xAA each launch)
    for (int i = gtid; i < 65536; i += 32768) { h[i] = 0.f; c[i] = 0.f; }
    if (gtid < 768) s3[gtid] = 0.f;

    // score_x[b,n] = sum_t x[b,t,n] * Wx[t]  (Wx = attn_W[2H .. 2H+T1))
    const int b = gtid >> 7;
    const int n = gtid & 127;
    const float* Wx = attn_W + 2 * HH;
    const float* xp = x + (size_t)b * TT * NN + n;
    float a0 = 0.f, a1 = 0.f, a2 = 0.f, a3 = 0.f;
    int t = 0;
    for (; t + 4 <= TT; t += 4) {
        a0 += xp[(size_t)(t + 0) * NN] * Wx[t + 0];
        a1 += xp[(size_t)(t + 1) * NN] * Wx[t + 1];
        a2 += xp[(size_t)(t + 2) * NN] * Wx[t + 2];
        a3 += xp[(size_t)(t + 3) * NN] * Wx[t + 3];
    }
    for (; t < TT; ++t) a0 += xp[(size_t)t * NN] * Wx[t];
    const float sc = (a0 + a1) + (a2 + a3) + attn_b[0];
    E[gtid] = __expf(sc);
}

// One kernel per timestep. Grid = 256 blocks = 8 b-tiles (32 rows) x 32 j-tiles (8 hidden cols x 4 gates).
__global__ __launch_bounds__(256) void step_kernel(
    const float* __restrict__ x, const float* __restrict__ attn_W,
    const float* __restrict__ W_ih, const float* __restrict__ W_hh,
    const float* __restrict__ b_ih, const float* __restrict__ b_hh,
    float* __restrict__ ws, float* __restrict__ out_w, float* __restrict__ out_e,
    int t)
{
    // 388-float row pitch: row-to-row bank shift = 388 % 32 = 4 banks, so the 8
    // distinct rows read per wave land on disjoint 4-bank groups (conflict-free b128).
    __shared__ float es_lds[256];
    __shared__ float denp[2][128];
    __shared__ float A_lds[32][388];       // cols 0..127 = w_in, 128..383 = h
    __shared__ float W_lds[32][388];       // cols 0..127 = W_ih, 128..383 = W_hh
    __shared__ float part_lds[4][32][36];  // per-wave K-split partials

    float* E  = ws;
    float* h  = ws + 32768;
    float* c  = ws + 98304;
    float* s3 = ws + 163840;
    const float* s_cur = s3 + (size_t)(t % 3) * 256;
    float*       s_nxt = s3 + (size_t)((t + 1) % 3) * 256;
    float*       s_zro = s3 + (size_t)((t + 2) % 3) * 256;

    const int tid    = threadIdx.x;
    const int bt     = blockIdx.x >> 5;   // 0..7
    const int jt     = blockIdx.x & 31;   // 0..31
    const int bbase  = bt * 32;
    const int hhbase = jt * 8;

    // ---- phase 1: es[b] = exp(s[b]) ; zero the (t+2) s-buffer (no reader this step)
    es_lds[tid] = __expf(s_cur[tid]);
    if (blockIdx.x == 0) s_zro[tid] = 0.f;
    __syncthreads();

    // ---- phase 2: stage W tile + h tile into LDS; softmax denominator partials
    // W_ih rows: 32 j x 128
#pragma unroll
    for (int i = 0; i < 4; ++i) {
        const int tp = i * 256 + tid;
        const int jl = tp >> 5, k4 = tp & 31;
        const int jg = (jl >> 3) * 256 + hhbase + (jl & 7);
        const float4 v = *(const float4*)&W_ih[(size_t)jg * NN + k4 * 4];
        *(float4*)&W_lds[jl][k4 * 4] = v;
    }
    // W_hh rows: 32 j x 256
#pragma unroll
    for (int i = 0; i < 8; ++i) {
        const int tp = i * 256 + tid;
        const int jl = tp >> 6, k4 = tp & 63;
        const int jg = (jl >> 3) * 256 + hhbase + (jl & 7);
        const float4 v = *(const float4*)&W_hh[(size_t)jg * HH + k4 * 4];
        *(float4*)&W_lds[jl][128 + k4 * 4] = v;
    }
    // h rows: 32 b x 256
#pragma unroll
    for (int i = 0; i < 8; ++i) {
        const int tp = i * 256 + tid;
        const int bl = tp >> 6, k4 = tp & 63;
        const float4 v = *(const float4*)&h[(size_t)(bbase + bl) * HH + k4 * 4];
        *(float4*)&A_lds[bl][128 + k4 * 4] = v;
    }
    // den[n] = sum_b E[b,n] * es[b]  (each half of the block does 128 b's)
    {
        const int n = tid & 127, half = tid >> 7;
        const float* Ep = E + (size_t)half * 128 * NN + n;
        float d0 = 0.f, d1 = 0.f, d2 = 0.f, d3 = 0.f;
#pragma unroll 8
        for (int bb = 0; bb < 128; bb += 4) {
            d0 += Ep[(size_t)(bb + 0) * NN] * es_lds[half * 128 + bb + 0];
            d1 += Ep[(size_t)(bb + 1) * NN] * es_lds[half * 128 + bb + 1];
            d2 += Ep[(size_t)(bb + 2) * NN] * es_lds[half * 128 + bb + 2];
            d3 += Ep[(size_t)(bb + 3) * NN] * es_lds[half * 128 + bb + 3];
        }
        denp[half][n] = (d0 + d1) + (d2 + d3);
    }
    __syncthreads();

    // ---- phase 3: w_in = E*es*x/den  -> A_lds[:,0:128] and the input_weighted output
#pragma unroll
    for (int i = 0; i < 16; ++i) {
        const int tp = i * 256 + tid;
        const int bl = tp >> 7, n = tp & 127;
        const int bg = bbase + bl;
        const float den = denp[0][n] + denp[1][n];
        const float wv = E[(size_t)bg * NN + n] * es_lds[bg] *
                         x[((size_t)bg * TT + t) * NN + n] / den;
        A_lds[bl][n] = wv;
        out_w[((size_t)bg * TT + t) * NN + n] = wv;
    }
    __syncthreads();

    // ---- phase 4: GEMM  gates[32b x 32j] = A[32 x 384] * W[32 x 384]^T (per-wave K-split)
    const int w    = tid >> 6;
    const int lane = tid & 63;
    const int bi   = lane & 7;     // 8 distinct b rows per wave
    const int ji   = lane >> 3;    // 8 distinct j rows per wave
    float acc[4][4] = {};
    const int k0 = w * 96;
#pragma unroll 2
    for (int kk = 0; kk < 96; kk += 4) {
        float4 av[4], wv[4];
#pragma unroll
        for (int u = 0; u < 4; ++u) av[u] = *(const float4*)&A_lds[bi + 8 * u][k0 + kk];
#pragma unroll
        for (int v = 0; v < 4; ++v) wv[v] = *(const float4*)&W_lds[ji + 8 * v][k0 + kk];
#pragma unroll
        for (int u = 0; u < 4; ++u)
#pragma unroll
            for (int v = 0; v < 4; ++v)
                acc[u][v] += av[u].x * wv[v].x + av[u].y * wv[v].y +
                             av[u].z * wv[v].z + av[u].w * wv[v].w;
    }
#pragma unroll
    for (int u = 0; u < 4; ++u)
#pragma unroll
        for (int v = 0; v < 4; ++v)
            part_lds[w][bi + 8 * u][ji + 8 * v] = acc[u][v];
    __syncthreads();

    // ---- phase 5: K-combine + biases + LSTM pointwise + outputs + next-step s atomics
    {
        const int bl = tid >> 3, hhl = tid & 7;
        const int bg = bbase + bl, hg = hhbase + hhl;
        float gate[4];
#pragma unroll
        for (int g = 0; g < 4; ++g) {
            const int jl = g * 8 + hhl;
            float sum = 0.f;
#pragma unroll
            for (int w2 = 0; w2 < 4; ++w2) sum += part_lds[w2][bl][jl];
            const int jg = g * 256 + hg;
            gate[g] = sum + b_ih[jg] + b_hh[jg];
        }
        const float co = c[(size_t)bg * HH + hg];
        const float ig = sigmoidf_(gate[0]);
        const float fg = sigmoidf_(gate[1]);
        const float gg = tanhf(gate[2]);
        const float og = sigmoidf_(gate[3]);
        const float cn = fg * co + ig * gg;
        const float hn = og * tanhf(cn);
        c[(size_t)bg * HH + hg] = cn;
        h[(size_t)bg * HH + hg] = hn;
        out_e[((size_t)bg * TT + t) * HH + hg] = hn;

        // partial s_next[b] = sum_hh h_new*Wh[hh] + c_new*Wc[hh] over this block's 8 hh
        float sp = hn * attn_W[hg] + cn * attn_W[HH + hg];
        sp += __shfl_xor(sp, 1);
        sp += __shfl_xor(sp, 2);
        sp += __shfl_xor(sp, 4);
        if (hhl == 0) atomicAdd(&s_nxt[bg], sp);
    }
}

extern "C" void kernel_launch(void* const* d_in, const int* in_sizes, int n_in,
                              void* d_out, int out_size, void* d_ws, size_t ws_size,
                              hipStream_t stream)
{
    const float* x      = (const float*)d_in[0];
    const float* attn_W = (const float*)d_in[1];
    const float* attn_b = (const float*)d_in[2];
    const float* W_ih   = (const float*)d_in[3];
    const float* W_hh   = (const float*)d_in[4];
    const float* b_ih   = (const float*)d_in[5];
    const float* b_hh   = (const float*)d_in[6];

    float* ws    = (float*)d_ws;
    float* out_w = (float*)d_out;                       // input_weighted [B][T1][N]
    float* out_e = out_w + (size_t)BB * TT * NN;        // input_encoded  [B][T1][H]

    precompute_kernel<<<128, 256, 0, stream>>>(x, attn_W, attn_b, ws);
    for (int t = 0; t < TT; ++t) {
        step_kernel<<<256, 256, 0, stream>>>(x, attn_W, W_ih, W_hh, b_ih, b_hh,
                                             ws, out_w, out_e, t);
    }
}